// Round 7
// baseline (285.791 us; speedup 1.0000x reference)
//
#include <hip/hip_runtime.h>
#include <math.h>

#define D_MODEL 1024
#define NUM_EXPERTS 8
#define TOP_K 2
#define TPW 8                         // tokens per wave
#define WAVES_PER_BLOCK 4
#define TOKENS_PER_BLOCK (TPW * WAVES_PER_BLOCK)   // 32

typedef float f4 __attribute__((ext_vector_type(4)));

// R7 "expert-split": no LDS in the main loop. lane = e*8+s; lane holds
// W[e] dims {p*128 + j*32 + s*4 ..+4} in 4 f4 regs (reloaded per pass,
// L2-hot). x-load inst: 8 s-lanes cover 128B contiguous, 8 e-dup lanes
// same-address (TA dedup -> HBM 1x). acc=8 floats; reduce = 3 butterfly
// steps over s. No staging barrier; 1KB LDS; 16 waves/CU; VGPR capped 128
// so the unrolled 256-load body keeps deep MLP without spills.
__global__ __launch_bounds__(256, 4) void gating_kernel(
    const float* __restrict__ x, const float* __restrict__ W,
    const float* __restrict__ b, float* __restrict__ out_w,
    float* __restrict__ out_idx, int n_tokens)
{
    __shared__ float scratch[WAVES_PER_BLOCK][NUM_EXPERTS][TPW];  // 1 KB

    const int wave = threadIdx.x >> 6;
    const int lane = threadIdx.x & 63;
    const int e = lane >> 3;          // expert 0..7
    const int s = lane & 7;           // dim-slice 0..7
    const int tok0 = blockIdx.x * TOKENS_PER_BLOCK + wave * TPW;

    const f4* Wf = (const f4*)(W + (size_t)e * D_MODEL);     // idx: p*32 + j*8 + s
    const f4* xf = (const f4*)(x + (size_t)tok0 * D_MODEL);  // + t*256 + p*32 + j*8 + s

    float acc[TPW];
#pragma unroll
    for (int t = 0; t < TPW; ++t) acc[t] = 0.f;

#pragma unroll
    for (int p = 0; p < 8; ++p) {
        f4 wv[4];
#pragma unroll
        for (int j = 0; j < 4; ++j) wv[j] = Wf[p * 32 + j * 8 + s];  // L2-hot, cached
#pragma unroll
        for (int t = 0; t < TPW; ++t) {
            f4 xv[4];
#pragma unroll
            for (int j = 0; j < 4; ++j)
                xv[j] = __builtin_nontemporal_load(xf + t * 256 + p * 32 + j * 8 + s);
#pragma unroll
            for (int j = 0; j < 4; ++j)
                acc[t] += xv[j].x * wv[j].x + xv[j].y * wv[j].y +
                          xv[j].z * wv[j].z + xv[j].w * wv[j].w;
        }
    }

    // Reduce over the 8 s-lanes within each expert octet (3 steps).
#pragma unroll
    for (int t = 0; t < TPW; ++t) {
        float v = acc[t];
        v += __shfl_xor(v, 1, 64);
        v += __shfl_xor(v, 2, 64);
        v += __shfl_xor(v, 4, 64);
        acc[t] = v;
    }

    if (s == 0) {
#pragma unroll
        for (int t = 0; t < TPW; ++t) scratch[wave][e][t] = acc[t];
    }
    __syncthreads();  // wave-local dep only, but barrier is the safe idiom

    if (lane < TPW) {
        const int token = tok0 + lane;
        if (token < n_tokens) {
            float lg[NUM_EXPERTS];
#pragma unroll
            for (int ee = 0; ee < NUM_EXPERTS; ++ee)
                lg[ee] = scratch[wave][ee][lane] + b[ee];   // b[ee]: s_load

            float v0 = -INFINITY, v1 = -INFINITY;
            int i0 = 0, i1 = 0;
#pragma unroll
            for (int ee = 0; ee < NUM_EXPERTS; ++ee) {
                float v = lg[ee];
                // strict > keeps lowest index on ties, matching jax.lax.top_k
                if (v > v0) { v1 = v0; i1 = i0; v0 = v; i0 = ee; }
                else if (v > v1) { v1 = v; i1 = ee; }
            }
            const float e1 = expf(v1 - v0);
            const float w0 = 1.f / (1.f + e1);
            const float w1 = e1 * w0;

            f4 o0, o1;
            o0.x = (0 == i0) ? w0 : ((0 == i1) ? w1 : 0.f);
            o0.y = (1 == i0) ? w0 : ((1 == i1) ? w1 : 0.f);
            o0.z = (2 == i0) ? w0 : ((2 == i1) ? w1 : 0.f);
            o0.w = (3 == i0) ? w0 : ((3 == i1) ? w1 : 0.f);
            o1.x = (4 == i0) ? w0 : ((4 == i1) ? w1 : 0.f);
            o1.y = (5 == i0) ? w0 : ((5 == i1) ? w1 : 0.f);
            o1.z = (6 == i0) ? w0 : ((6 == i1) ? w1 : 0.f);
            o1.w = (7 == i0) ? w0 : ((7 == i1) ? w1 : 0.f);
            f4* dst = (f4*)(out_w + (size_t)token * NUM_EXPERTS);
            dst[0] = o0;
            dst[1] = o1;
            *(float2*)(out_idx + (size_t)token * TOP_K) =
                make_float2((float)i0, (float)i1);
        }
    }
}

extern "C" void kernel_launch(void* const* d_in, const int* in_sizes, int n_in,
                              void* d_out, int out_size, void* d_ws, size_t ws_size,
                              hipStream_t stream) {
    const float* x = (const float*)d_in[0];
    const float* W = (const float*)d_in[1];
    const float* b = (const float*)d_in[2];
    float* out = (float*)d_out;

    const int n_tokens = in_sizes[0] / D_MODEL;              // 32768
    float* out_w   = out;                                    // [n_tokens, 8]
    float* out_idx = out + (size_t)n_tokens * NUM_EXPERTS;   // [n_tokens, 2] as float

    const int grid = (n_tokens + TOKENS_PER_BLOCK - 1) / TOKENS_PER_BLOCK;  // 1024
    gating_kernel<<<grid, 256, 0, stream>>>(x, W, b, out_w, out_idx, n_tokens);
}

// Round 8
// 217.449 us; speedup vs baseline: 1.3143x; 1.3143x over previous
//
#include <hip/hip_runtime.h>
#include <math.h>

#define D_MODEL 1024
#define NUM_EXPERTS 8
#define TOP_K 2
#define TPW 4                         // tokens per wave (16 lanes each)
#define WAVES_PER_BLOCK 4
#define TOKENS_PER_BLOCK (TPW * WAVES_PER_BLOCK)   // 16

typedef float f4 __attribute__((ext_vector_type(4)));

// R8: zero-LDS streaming kernel. lane = t*16+l; wave owns 4 tokens; 16
// slices of 64 dims. x-load inst = 64 lanes x 16B distinct = 1KB useful
// (4 contiguous 256B runs), NT so W stays cached. W slice = 8 f4/lane
// (16-lane contiguous, 4-way dup dedup'd), reloaded per slice; W = 32KB
// = L1-resident. No barrier, no LDS cap; launch_bounds(256,8) -> <=64
// VGPR -> 8 waves/SIMD, 32 waves/CU: latency hidden by TLP. Per-CU:
// VALU ~3.7us, VMEM issue ~2us, HBM stream ~21us -> HBM-bound.
__global__ __launch_bounds__(256, 8) void gating_kernel(
    const float* __restrict__ x, const float* __restrict__ W,
    const float* __restrict__ b, float* __restrict__ out_w,
    float* __restrict__ out_idx, int n_tokens)
{
    const int wave = threadIdx.x >> 6;
    const int lane = threadIdx.x & 63;
    const int t = lane >> 4;          // token-in-wave 0..3
    const int l = lane & 15;          // dim-slice lane 0..15
    const int token = blockIdx.x * TOKENS_PER_BLOCK + wave * TPW + t;
    if (token >= n_tokens) return;

    const f4* xf = (const f4*)x + (size_t)token * (D_MODEL / 4) + l;  // + s*16
    const f4* Wf = (const f4*)W + l;                                  // + e*256 + s*16

    float acc[NUM_EXPERTS];
#pragma unroll
    for (int e = 0; e < NUM_EXPERTS; ++e) acc[e] = 0.f;

    f4 xc = __builtin_nontemporal_load(xf);   // slice 0
#pragma unroll
    for (int s = 0; s < 16; ++s) {
        f4 xn;
        if (s < 15) xn = __builtin_nontemporal_load(xf + (s + 1) * 16);
#pragma unroll
        for (int e = 0; e < NUM_EXPERTS; ++e) {
            const f4 wv = Wf[e * 256 + s * 16];   // L1/L2-hot, 256B/inst
            acc[e] += xc.x * wv.x + xc.y * wv.y + xc.z * wv.z + xc.w * wv.w;
        }
        xc = xn;
    }

    // Butterfly over the 16 lanes of the token group (xor 1,2,4,8 keeps t).
#pragma unroll
    for (int e = 0; e < NUM_EXPERTS; ++e) {
        float v = acc[e];
        v += __shfl_xor(v, 1, 64);
        v += __shfl_xor(v, 2, 64);
        v += __shfl_xor(v, 4, 64);
        v += __shfl_xor(v, 8, 64);
        acc[e] = v + b[e];            // b: uniform ptr, constant idx -> s_load
    }

    // All 16 lanes hold full logits; top-2 + 2-way softmax.
    float v0 = -INFINITY, v1 = -INFINITY;
    int i0 = 0, i1 = 0;
#pragma unroll
    for (int e = 0; e < NUM_EXPERTS; ++e) {
        float v = acc[e];
        // strict > keeps lowest index on ties, matching jax.lax.top_k
        if (v > v0) { v1 = v0; i1 = i0; v0 = v; i0 = e; }
        else if (v > v1) { v1 = v; i1 = e; }
    }
    const float e1 = expf(v1 - v0);
    const float w0 = 1.f / (1.f + e1);
    const float w1 = e1 * w0;

    if (l < 2) {                       // two lanes write the 2 f4 halves
        const int base = l * 4;
        f4 v4;
        v4.x = (base + 0 == i0) ? w0 : ((base + 0 == i1) ? w1 : 0.f);
        v4.y = (base + 1 == i0) ? w0 : ((base + 1 == i1) ? w1 : 0.f);
        v4.z = (base + 2 == i0) ? w0 : ((base + 2 == i1) ? w1 : 0.f);
        v4.w = (base + 3 == i0) ? w0 : ((base + 3 == i1) ? w1 : 0.f);
        ((f4*)(out_w + (size_t)token * NUM_EXPERTS))[l] = v4;
    } else if (l == 2) {
        *(float2*)(out_idx + (size_t)token * TOP_K) =
            make_float2((float)i0, (float)i1);
    }
}

extern "C" void kernel_launch(void* const* d_in, const int* in_sizes, int n_in,
                              void* d_out, int out_size, void* d_ws, size_t ws_size,
                              hipStream_t stream) {
    const float* x = (const float*)d_in[0];
    const float* W = (const float*)d_in[1];
    const float* b = (const float*)d_in[2];
    float* out = (float*)d_out;

    const int n_tokens = in_sizes[0] / D_MODEL;              // 32768
    float* out_w   = out;                                    // [n_tokens, 8]
    float* out_idx = out + (size_t)n_tokens * NUM_EXPERTS;   // [n_tokens, 2] as float

    const int grid = (n_tokens + TOKENS_PER_BLOCK - 1) / TOKENS_PER_BLOCK;  // 2048
    gating_kernel<<<grid, 256, 0, stream>>>(x, W, b, out_w, out_idx, n_tokens);
}

// Round 9
// 186.822 us; speedup vs baseline: 1.5297x; 1.1639x over previous
//
#include <hip/hip_runtime.h>
#include <math.h>

#define D_MODEL 1024
#define NUM_EXPERTS 8
#define TOP_K 2
#define TOKENS_PER_WAVE 8
#define WAVES_PER_BLOCK 4
#define TOKENS_PER_BLOCK (TOKENS_PER_WAVE * WAVES_PER_BLOCK)  // 32

typedef float f4 __attribute__((ext_vector_type(4)));

// R9 = R4 (best: ~43us kernel) + ONE variable: 1-chunk-ahead x pipeline.
// lane = g*8+l; group g owns one token; lane l covers f4 idx l + kk*8.
// R4 drained vmcnt(0) before each chunk's FMAs (load-issue duty ~50%);
// here chunk c+1's 8 loads are in flight while chunk c computes, so the
// x stream never stalls. Buffer 2x8 f4 = 64 VGPR, total ~90 -> still
// 4 waves/SIMD; grid 1024 = 4 blocks/CU (LDS 32KB caps 5), 16 waves/CU.
__global__ __launch_bounds__(256) void gating_kernel(
    const float* __restrict__ x, const float* __restrict__ W,
    const float* __restrict__ b, float* __restrict__ out_w,
    float* __restrict__ out_idx, int n_tokens)
{
    __shared__ float Wlds[NUM_EXPERTS * D_MODEL];  // 32 KB

    {   // stage W: 2048 f4 across 256 threads -> 8 each
        const f4* Wg = (const f4*)W;
        f4* Ws = (f4*)Wlds;
        const int tid = threadIdx.x;
#pragma unroll
        for (int i = 0; i < (NUM_EXPERTS * D_MODEL / 4) / 256; ++i)
            Ws[tid + i * 256] = Wg[tid + i * 256];
    }
    __syncthreads();

    const int wave = threadIdx.x >> 6;
    const int lane = threadIdx.x & 63;
    const int g = lane >> 3;          // group / token-in-wave 0..7
    const int l = lane & 7;           // lane-in-group 0..7
    const int token = blockIdx.x * TOKENS_PER_BLOCK + wave * TOKENS_PER_WAVE + g;
    if (token >= n_tokens) return;

    const f4* xg = (const f4*)x + (size_t)token * (D_MODEL / 4) + l;  // + kk*8
    const f4* Wf = (const f4*)Wlds + l;                               // + e*256 + kk*8

    float acc[NUM_EXPERTS];
#pragma unroll
    for (int e = 0; e < NUM_EXPERTS; ++e) acc[e] = 0.f;

    // 4 chunks of 8 kk; double-buffered so 8 loads stay in flight during
    // each chunk's 64 ds_read + 256 v_fma.
    f4 buf[2][8];
#pragma unroll
    for (int kk = 0; kk < 8; ++kk)
        buf[0][kk] = __builtin_nontemporal_load(xg + kk * 8);

#pragma unroll
    for (int c = 0; c < 4; ++c) {
        const int cur = c & 1, nxt = cur ^ 1;
        if (c < 3) {
#pragma unroll
            for (int kk = 0; kk < 8; ++kk)
                buf[nxt][kk] = __builtin_nontemporal_load(xg + (c + 1) * 64 + kk * 8);
        }
#pragma unroll
        for (int e = 0; e < NUM_EXPERTS; ++e) {
            float s = acc[e];
#pragma unroll
            for (int kk = 0; kk < 8; ++kk) {
                const f4 wv = Wf[e * 256 + (c * 8 + kk) * 8];
                const f4 xv = buf[cur][kk];
                s += xv.x * wv.x + xv.y * wv.y + xv.z * wv.z + xv.w * wv.w;
            }
            acc[e] = s;
        }
    }

    // Reduce across the 8 lanes of the group (3 butterfly steps), add bias.
#pragma unroll
    for (int e = 0; e < NUM_EXPERTS; ++e) {
        float v = acc[e];
        v += __shfl_xor(v, 1, 64);
        v += __shfl_xor(v, 2, 64);
        v += __shfl_xor(v, 4, 64);
        acc[e] = v + b[e];
    }

    // Every lane of the group holds the full logits; top-2 + 2-way softmax.
    float v0 = -INFINITY, v1 = -INFINITY;
    int i0 = 0, i1 = 0;
#pragma unroll
    for (int e = 0; e < NUM_EXPERTS; ++e) {
        float v = acc[e];
        // strict > keeps lowest index on ties, matching jax.lax.top_k
        if (v > v0) { v1 = v0; i1 = i0; v0 = v; i0 = e; }
        else if (v > v1) { v1 = v; i1 = e; }
    }
    const float e1 = expf(v1 - v0);
    const float w0 = 1.f / (1.f + e1);
    const float w1 = e1 * w0;

    if (l < 2) {
        const int base = l * 4;
        f4 v4;
        v4.x = (base + 0 == i0) ? w0 : ((base + 0 == i1) ? w1 : 0.f);
        v4.y = (base + 1 == i0) ? w0 : ((base + 1 == i1) ? w1 : 0.f);
        v4.z = (base + 2 == i0) ? w0 : ((base + 2 == i1) ? w1 : 0.f);
        v4.w = (base + 3 == i0) ? w0 : ((base + 3 == i1) ? w1 : 0.f);
        ((f4*)(out_w + (size_t)token * NUM_EXPERTS))[l] = v4;
    } else if (l == 2) {
        *(float2*)(out_idx + (size_t)token * TOP_K) =
            make_float2((float)i0, (float)i1);
    }
}

extern "C" void kernel_launch(void* const* d_in, const int* in_sizes, int n_in,
                              void* d_out, int out_size, void* d_ws, size_t ws_size,
                              hipStream_t stream) {
    const float* x = (const float*)d_in[0];
    const float* W = (const float*)d_in[1];
    const float* b = (const float*)d_in[2];
    float* out = (float*)d_out;

    const int n_tokens = in_sizes[0] / D_MODEL;              // 32768
    float* out_w   = out;                                    // [n_tokens, 8]
    float* out_idx = out + (size_t)n_tokens * NUM_EXPERTS;   // [n_tokens, 2] as float

    const int grid = (n_tokens + TOKENS_PER_BLOCK - 1) / TOKENS_PER_BLOCK;  // 1024
    gating_kernel<<<grid, 256, 0, stream>>>(x, W, b, out_w, out_idx, n_tokens);
}